// Round 1
// baseline (5898.575 us; speedup 1.0000x reference)
//
#include <hip/hip_runtime.h>
#include <hip/hip_bf16.h>

#define NN 100000      // nodes graph 1
#define MMn 200000     // nodes graph 2 (link nodes)
#define DD 64
#define NE1 3200000
#define NE2 3200000

static inline int cdiv_l(long a, long b) { return (int)((a + b - 1) / b); }

// ---------- generic fill ----------
__global__ void fill_f32_k(float* p, float v, long n) {
    long i = (long)blockIdx.x * blockDim.x + threadIdx.x;
    long st = (long)gridDim.x * blockDim.x;
    for (; i < n; i += st) p[i] = v;
}

// ---------- degree count (deg starts at 1.0 for self loop) ----------
__global__ void count_deg_k(const int* __restrict__ col, int ne, float* deg) {
    int i = blockIdx.x * blockDim.x + threadIdx.x;
    if (i < ne) atomicAdd(&deg[col[i]], 1.0f);
}

__global__ void rsqrt_k(float* p, int n) {
    int i = blockIdx.x * blockDim.x + threadIdx.x;
    if (i < n) p[i] = rsqrtf(p[i]);
}

// ---------- embedding gather ----------
__global__ void embed_k(const int* __restrict__ x, const float* __restrict__ tab,
                        float* __restrict__ h, int nrows) {
    long i = (long)blockIdx.x * blockDim.x + threadIdx.x;
    long tot = (long)nrows * DD;
    if (i >= tot) return;
    int r = (int)(i >> 6), d = (int)(i & 63);
    h[i] = tab[x[r] * DD + d];
}

// ---------- H(nx64) @ W(64x64) ----------
__global__ __launch_bounds__(256) void matmul64_k(const float* __restrict__ Hin,
                                                  const float* __restrict__ W,
                                                  float* __restrict__ Hout, int nrows) {
    __shared__ float sW[64 * 64];
    __shared__ float sH[4 * 64];
    int tid = threadIdx.x;
    for (int i = tid; i < 4096; i += 256) sW[i] = W[i];
    __syncthreads();
    int rb = blockIdx.x * 32;
    int lr = tid >> 6, c = tid & 63;
    for (int it = 0; it < 8; ++it) {
        int r = rb + it * 4 + lr;
        __syncthreads();
        sH[lr * 64 + c] = (r < nrows) ? Hin[(long)r * 64 + c] : 0.f;
        __syncthreads();
        float acc = 0.f;
#pragma unroll
        for (int k = 0; k < 64; ++k) acc = fmaf(sH[lr * 64 + k], sW[k * 64 + c], acc);
        if (r < nrows) Hout[(long)r * 64 + c] = acc;
    }
}

// ---------- GCN: self-loop init  agg = xw*dinv^2 + bias ----------
__global__ void scatter_init_k(const float* __restrict__ xw, const float* __restrict__ dinv,
                               const float* __restrict__ bias, float* __restrict__ agg, int nrows) {
    long i = (long)blockIdx.x * blockDim.x + threadIdx.x;
    long tot = (long)nrows * DD;
    if (i >= tot) return;
    int r = (int)(i >> 6), d = (int)(i & 63);
    float di = dinv[r];
    agg[i] = xw[i] * di * di + bias[d];
}

// ---------- GCN: edge scatter, one wave per edge (lane = feature dim) ----------
__global__ void scatter_edges_k(const int* __restrict__ rowv, const int* __restrict__ colv, int ne,
                                const float* __restrict__ xw, const float* __restrict__ dinv,
                                float* __restrict__ agg) {
    long t = (long)blockIdx.x * blockDim.x + threadIdx.x;
    long tot = (long)ne * DD;
    if (t >= tot) return;
    int e = (int)(t >> 6), d = (int)(t & 63);
    int r = rowv[e], c = colv[e];
    float s = dinv[r] * dinv[c];
    atomicAdd(&agg[(long)c * DD + d], xw[(long)r * DD + d] * s);
}

// ---------- GraphNorm column stats (sum, sumsq) ----------
__global__ __launch_bounds__(256) void gn_stats_k(const float* __restrict__ x, long nrows,
                                                  float* __restrict__ stats) {
    __shared__ float sS[256], sQ[256];
    int tid = threadIdx.x;
    int d = tid & 63;
    float s = 0.f, q = 0.f;
    long tot = nrows * DD;
    for (long i = (long)blockIdx.x * blockDim.x + tid; i < tot; i += (long)gridDim.x * blockDim.x) {
        float v = x[i];
        s += v; q += v * v;
    }
    sS[tid] = s; sQ[tid] = q;
    __syncthreads();
    if (tid < 128) { sS[tid] += sS[tid + 128]; sQ[tid] += sQ[tid + 128]; }
    __syncthreads();
    if (tid < 64) {
        atomicAdd(&stats[d], sS[tid] + sS[tid + 64]);
        atomicAdd(&stats[64 + d], sQ[tid] + sQ[tid + 64]);
    }
}

// ---------- GraphNorm apply. mode: 0 = write, 1 = relu write, 2 = relu accumulate ----------
__global__ void gn_norm_k(const float* __restrict__ x, float* __restrict__ y,
                          const float* __restrict__ stats, const float* __restrict__ w,
                          const float* __restrict__ b, const float* __restrict__ ms,
                          long nrows, int mode) {
    long i = (long)blockIdx.x * blockDim.x + threadIdx.x;
    long tot = nrows * DD;
    if (i >= tot) return;
    int d = (int)(i & 63);
    float n = (float)nrows;
    float mean = stats[d] / n;
    float ex2 = stats[64 + d] / n;
    float m = ms[d];
    float var = ex2 - mean * mean * (2.f * m - m * m);
    float is = rsqrtf(var + 1e-5f);
    float v = (x[i] - m * mean) * is * w[d] + b[d];
    if (mode >= 1) v = fmaxf(v, 0.f);
    if (mode == 2) y[i] += v; else y[i] = v;
}

// ---------- link-pair elementwise product (pos1) ----------
__global__ void pair_mul_k(const float* __restrict__ h, const int* __restrict__ pos,
                           float* __restrict__ y, int nrows) {
    long i = (long)blockIdx.x * blockDim.x + threadIdx.x;
    long tot = (long)nrows * DD;
    if (i >= tot) return;
    int r = (int)(i >> 6), d = (int)(i & 63);
    int p0 = pos[2 * r], p1 = pos[2 * r + 1];
    y[i] = h[(long)p0 * DD + d] * h[(long)p1 * DD + d];
}

// ---------- final: gather pos2 pairs, product, dot with pred_W ----------
__global__ __launch_bounds__(256) void final_k(const float* __restrict__ h, const int* __restrict__ pos2,
                                               const float* __restrict__ pw, const float* __restrict__ pb,
                                               float* __restrict__ out, int nout) {
    long t = (long)blockIdx.x * blockDim.x + threadIdx.x;
    long tot = (long)nout * DD;
    if (t >= tot) return;
    int i = (int)(t >> 6), d = (int)(t & 63);
    int p0 = pos2[2 * i], p1 = pos2[2 * i + 1];
    float v = h[(long)p0 * DD + d] * h[(long)p1 * DD + d] * pw[d];
#pragma unroll
    for (int o = 32; o > 0; o >>= 1) v += __shfl_down(v, o, 64);
    if (d == 0) out[i] = v + pb[0];
}

extern "C" void kernel_launch(void* const* d_in, const int* in_sizes, int n_in,
                              void* d_out, int out_size, void* d_ws, size_t ws_size,
                              hipStream_t stream) {
    const int* x      = (const int*)d_in[0];
    const int* edge1  = (const int*)d_in[2];
    const int* edge2  = (const int*)d_in[3];
    const int* edge2r = (const int*)d_in[4];
    const int* pos1   = (const int*)d_in[5];
    const int* pos2   = (const int*)d_in[6];
    const float* emb  = (const float*)d_in[7];
    const float* egw  = (const float*)d_in[8];
    const float* egb  = (const float*)d_in[9];
    const float* egm  = (const float*)d_in[10];
    const float* c1W  = (const float*)d_in[11];
    const float* c1b  = (const float*)d_in[12];
    const float* c1gw = (const float*)d_in[13];
    const float* c1gb = (const float*)d_in[14];
    const float* c1gm = (const float*)d_in[15];
    const float* c2W  = (const float*)d_in[16];
    const float* c2b  = (const float*)d_in[17];
    const float* c2gw = (const float*)d_in[18];
    const float* c2gb = (const float*)d_in[19];
    const float* c2gm = (const float*)d_in[20];
    const float* c2rW  = (const float*)d_in[21];
    const float* c2rb  = (const float*)d_in[22];
    const float* c2rgw = (const float*)d_in[23];
    const float* c2rgb = (const float*)d_in[24];
    const float* c2rgm = (const float*)d_in[25];
    const float* predW = (const float*)d_in[26];
    const float* predb = (const float*)d_in[27];
    float* out = (float*)d_out;

    const long SZ = (long)MMn * DD;              // 12.8M floats per node buffer
    size_t need = (3 * SZ + NN + 2 * MMn + 256) * sizeof(float);
    if (ws_size < need) return;

    float* base  = (float*)d_ws;
    float* B0    = base;
    float* B1    = base + SZ;
    float* B2    = base + 2 * SZ;
    float* dinv1 = base + 3 * SZ;
    float* dinv2 = dinv1 + NN;
    float* dinv2r = dinv2 + MMn;
    float* statsA = dinv2r + MMn;
    float* statsB = statsA + 128;

    // ---- degrees -> dinv (edge lists are constant per call) ----
    fill_f32_k<<<1024, 256, 0, stream>>>(dinv1, 1.0f, (long)(NN + 2 * MMn));
    count_deg_k<<<cdiv_l(NE1, 256), 256, 0, stream>>>(edge1 + NE1, NE1, dinv1);
    count_deg_k<<<cdiv_l(NE2, 256), 256, 0, stream>>>(edge2 + NE2, NE2, dinv2);
    count_deg_k<<<cdiv_l(NE2, 256), 256, 0, stream>>>(edge2r + NE2, NE2, dinv2r);
    rsqrt_k<<<cdiv_l(NN + 2 * MMn, 256), 256, 0, stream>>>(dinv1, NN + 2 * MMn);

    // ---- embedding + GraphNorm ----
    embed_k<<<cdiv_l((long)NN * DD, 256), 256, 0, stream>>>(x, emb, B0, NN);
    fill_f32_k<<<1, 256, 0, stream>>>(statsA, 0.f, 256);
    gn_stats_k<<<2048, 256, 0, stream>>>(B0, NN, statsA);
    gn_norm_k<<<cdiv_l((long)NN * DD, 256), 256, 0, stream>>>(B0, B0, statsA, egw, egb, egm, NN, 0);

    // ---- conv1 stack on graph 1 (h in B0, scratch B1/B2) ----
    for (int l = 0; l < 2; ++l) {
        matmul64_k<<<cdiv_l(NN, 32), 256, 0, stream>>>(B0, c1W + (long)l * 4096, B1, NN);
        scatter_init_k<<<cdiv_l((long)NN * DD, 256), 256, 0, stream>>>(B1, dinv1, c1b + l * 64, B2, NN);
        scatter_edges_k<<<cdiv_l((long)NE1 * DD, 256), 256, 0, stream>>>(edge1, edge1 + NE1, NE1, B1, dinv1, B2);
        fill_f32_k<<<1, 256, 0, stream>>>(statsA, 0.f, 256);
        gn_stats_k<<<2048, 256, 0, stream>>>(B2, NN, statsA);
        gn_norm_k<<<cdiv_l((long)NN * DD, 256), 256, 0, stream>>>(B2, B0, statsA, c1gw + l * 64, c1gb + l * 64, c1gm + l * 64, NN, 1);
    }

    // ---- link-pair product -> M-row h in B2 ----
    pair_mul_k<<<cdiv_l((long)MMn * DD, 256), 256, 0, stream>>>(B0, pos1, B2, MMn);

    // ---- dual-branch conv2 stack on graph 2; buffer rotation (h, f1, f2) ----
    float* h = B2; float* f1 = B0; float* f2 = B1;
    for (int l = 0; l < 2; ++l) {
        // branch a (edge2)
        matmul64_k<<<cdiv_l(MMn, 32), 256, 0, stream>>>(h, c2W + (long)l * 4096, f1, MMn);
        scatter_init_k<<<cdiv_l((long)MMn * DD, 256), 256, 0, stream>>>(f1, dinv2, c2b + l * 64, f2, MMn);
        scatter_edges_k<<<cdiv_l((long)NE2 * DD, 256), 256, 0, stream>>>(edge2, edge2 + NE2, NE2, f1, dinv2, f2);
        fill_f32_k<<<1, 256, 0, stream>>>(statsA, 0.f, 256);  // zeroes statsA+statsB
        gn_stats_k<<<2048, 256, 0, stream>>>(f2, MMn, statsA);
        gn_norm_k<<<cdiv_l((long)MMn * DD, 256), 256, 0, stream>>>(f2, f1, statsA, c2gw + l * 64, c2gb + l * 64, c2gm + l * 64, MMn, 1);
        // branch b (edge2 reversed); f1 now holds relu(gn(a)), accumulate into it
        matmul64_k<<<cdiv_l(MMn, 32), 256, 0, stream>>>(h, c2rW + (long)l * 4096, f2, MMn);
        scatter_init_k<<<cdiv_l((long)MMn * DD, 256), 256, 0, stream>>>(f2, dinv2r, c2rb + l * 64, h, MMn);
        scatter_edges_k<<<cdiv_l((long)NE2 * DD, 256), 256, 0, stream>>>(edge2r, edge2r + NE2, NE2, f2, dinv2r, h);
        gn_stats_k<<<2048, 256, 0, stream>>>(h, MMn, statsB);
        gn_norm_k<<<cdiv_l((long)MMn * DD, 256), 256, 0, stream>>>(h, f1, statsB, c2rgw + l * 64, c2rgb + l * 64, c2rgm + l * 64, MMn, 2);
        // rotate: new h = f1
        float* oldh = h; h = f1; f1 = f2; f2 = oldh;
    }

    // ---- pos2 pair product + linear head ----
    final_k<<<cdiv_l((long)out_size * DD, 256), 256, 0, stream>>>(h, pos2, predW, predb, out, out_size);
}

// Round 2
// 3146.933 us; speedup vs baseline: 1.8744x; 1.8744x over previous
//
#include <hip/hip_runtime.h>
#include <hip/hip_bf16.h>

#define NN 100000      // nodes graph 1
#define MMn 200000     // nodes graph 2 (link nodes)
#define DD 64
#define NE1 3200000
#define NE2 3200000

static inline int cdiv_l(long a, long b) { return (int)((a + b - 1) / b); }

// ---------- generic fill ----------
__global__ void fill_f32_k(float* p, float v, long n) {
    long i = (long)blockIdx.x * blockDim.x + threadIdx.x;
    long st = (long)gridDim.x * blockDim.x;
    for (; i < n; i += st) p[i] = v;
}

// ---------- degree count (fallback path; deg starts at 1.0 for self loop) ----------
__global__ void count_deg_k(const int* __restrict__ col, int ne, float* deg) {
    int i = blockIdx.x * blockDim.x + threadIdx.x;
    if (i < ne) atomicAdd(&deg[col[i]], 1.0f);
}

__global__ void rsqrt_k(float* p, int n) {
    int i = blockIdx.x * blockDim.x + threadIdx.x;
    if (i < n) p[i] = rsqrtf(p[i]);
}

// ---------- CSR build: histogram ----------
__global__ void hist_k(const int* __restrict__ col, int ne, int* __restrict__ cnt) {
    int i = blockIdx.x * blockDim.x + threadIdx.x;
    if (i < ne) atomicAdd(&cnt[col[i]], 1);
}

// ---------- dinv = rsqrt(cnt+1) ----------
__global__ void dinv_from_cnt_k(const int* __restrict__ cnt, float* __restrict__ dinv, int n) {
    int i = blockIdx.x * blockDim.x + threadIdx.x;
    if (i < n) dinv[i] = rsqrtf((float)cnt[i] + 1.0f);
}

// ---------- 2-level exclusive scan over cnt[0..n) -> off[0..n] ----------
__global__ __launch_bounds__(256) void scan_sums_k(const int* __restrict__ cnt, int n, int* __restrict__ bsum) {
    __shared__ int s[256];
    int b = blockIdx.x, t = threadIdx.x;
    int base = b * 1024 + t * 4;
    int T = 0;
#pragma unroll
    for (int j = 0; j < 4; ++j) { int i = base + j; if (i < n) T += cnt[i]; }
    s[t] = T; __syncthreads();
    for (int o = 128; o > 0; o >>= 1) { if (t < o) s[t] += s[t + o]; __syncthreads(); }
    if (t == 0) bsum[b] = s[0];
}

__global__ __launch_bounds__(256) void scan_tops_k(int* bsum, int nb) {
    __shared__ int s[256];
    int t = threadIdx.x;
    int v = (t < nb) ? bsum[t] : 0;
    s[t] = v; __syncthreads();
    for (int o = 1; o < 256; o <<= 1) {
        int x = (t >= o) ? s[t - o] : 0;
        __syncthreads();
        s[t] += x;
        __syncthreads();
    }
    if (t < nb) bsum[t] = s[t] - v;   // exclusive
}

__global__ __launch_bounds__(256) void scan_apply_k(const int* __restrict__ cnt, int n,
                                                    const int* __restrict__ bpre, int* __restrict__ off) {
    __shared__ int sT[256];
    int b = blockIdx.x, t = threadIdx.x;
    int base = b * 1024 + t * 4;
    int v[4]; int T = 0;
#pragma unroll
    for (int j = 0; j < 4; ++j) { int i = base + j; v[j] = (i < n) ? cnt[i] : 0; T += v[j]; }
    sT[t] = T; __syncthreads();
    for (int o = 1; o < 256; o <<= 1) {
        int x = (t >= o) ? sT[t - o] : 0;
        __syncthreads();
        sT[t] += x;
        __syncthreads();
    }
    int ex = sT[t] - T + bpre[b];
#pragma unroll
    for (int j = 0; j < 4; ++j) {
        int i = base + j;
        if (i < n) off[i] = ex;
        ex += v[j];
        if (i == n - 1) off[n] = ex;
    }
}

// ---------- CSR fill (consumes cnt via atomicSub) ----------
__global__ void csr_fill_k(const int* __restrict__ rowv, const int* __restrict__ colv, int ne,
                           const int* __restrict__ off, int* __restrict__ cnt, int* __restrict__ rows) {
    int i = blockIdx.x * blockDim.x + threadIdx.x;
    if (i >= ne) return;
    int c = colv[i];
    int old = atomicSub(&cnt[c], 1);
    rows[off[c] + old - 1] = rowv[i];
}

// ---------- embedding gather ----------
__global__ void embed_k(const int* __restrict__ x, const float* __restrict__ tab,
                        float* __restrict__ h, int nrows) {
    long i = (long)blockIdx.x * blockDim.x + threadIdx.x;
    long tot = (long)nrows * DD;
    if (i >= tot) return;
    int r = (int)(i >> 6), d = (int)(i & 63);
    h[i] = tab[x[r] * DD + d];
}

// ---------- GCN propagate: P[c] = (sum_{r in N(c)} h[r]*dinv[r] + h[c]*dinv[c]) * dinv[c] ----------
__global__ __launch_bounds__(256) void gcn_gather_k(const float* __restrict__ h,
                                                    const int* __restrict__ off,
                                                    const int* __restrict__ rows,
                                                    const float* __restrict__ dinv,
                                                    float* __restrict__ P, int n) {
    int node = blockIdx.x * 4 + (threadIdx.x >> 6);
    int d = threadIdx.x & 63;
    if (node >= n) return;
    int s = off[node], e = off[node + 1];
    float dc = dinv[node];
    float acc = h[(long)node * DD + d] * dc;   // self-loop term (x dc again at end)
    float acc2 = 0.f;
    int i = s;
    for (; i + 1 < e; i += 2) {
        int r0 = rows[i], r1 = rows[i + 1];
        float s0 = dinv[r0], s1 = dinv[r1];
        acc  = fmaf(h[(long)r0 * DD + d], s0, acc);
        acc2 = fmaf(h[(long)r1 * DD + d], s1, acc2);
    }
    if (i < e) {
        int r = rows[i];
        acc = fmaf(h[(long)r * DD + d], dinv[r], acc);
    }
    P[(long)node * DD + d] = (acc + acc2) * dc;
}

// ---------- H(nx64) @ W(64x64) + bias ; in-place safe (Hout may == Hin) ----------
__global__ __launch_bounds__(256) void matmul64_bias_k(const float* Hin, const float* __restrict__ W,
                                                       const float* __restrict__ bias,
                                                       float* Hout, int nrows) {
    __shared__ float sW[64 * 64];
    __shared__ float sH[4 * 64];
    int tid = threadIdx.x;
    for (int i = tid; i < 4096; i += 256) sW[i] = W[i];
    __syncthreads();
    int rb = blockIdx.x * 32;
    int lr = tid >> 6, c = tid & 63;
    float bc = bias[c];
    for (int it = 0; it < 8; ++it) {
        int r = rb + it * 4 + lr;
        __syncthreads();
        sH[lr * 64 + c] = (r < nrows) ? Hin[(long)r * 64 + c] : 0.f;
        __syncthreads();
        float acc = bc;
#pragma unroll
        for (int k = 0; k < 64; ++k) acc = fmaf(sH[lr * 64 + k], sW[k * 64 + c], acc);
        if (r < nrows) Hout[(long)r * 64 + c] = acc;
    }
}

// ---------- fallback (atomic) path kernels ----------
__global__ void scatter_self_k(const float* __restrict__ h, const float* __restrict__ dinv,
                               float* __restrict__ P, int nrows) {
    long i = (long)blockIdx.x * blockDim.x + threadIdx.x;
    long tot = (long)nrows * DD;
    if (i >= tot) return;
    int r = (int)(i >> 6);
    float di = dinv[r];
    P[i] = h[i] * di * di;
}

__global__ void scatter_edges_k(const int* __restrict__ rowv, const int* __restrict__ colv, int ne,
                                const float* __restrict__ h, const float* __restrict__ dinv,
                                float* __restrict__ P) {
    long t = (long)blockIdx.x * blockDim.x + threadIdx.x;
    long tot = (long)ne * DD;
    if (t >= tot) return;
    int e = (int)(t >> 6), d = (int)(t & 63);
    int r = rowv[e], c = colv[e];
    float s = dinv[r] * dinv[c];
    atomicAdd(&P[(long)c * DD + d], h[(long)r * DD + d] * s);
}

// ---------- GraphNorm column stats (sum, sumsq) ----------
__global__ __launch_bounds__(256) void gn_stats_k(const float* __restrict__ x, long nrows,
                                                  float* __restrict__ stats) {
    __shared__ float sS[256], sQ[256];
    int tid = threadIdx.x;
    int d = tid & 63;
    float s = 0.f, q = 0.f;
    long tot = nrows * DD;
    for (long i = (long)blockIdx.x * blockDim.x + tid; i < tot; i += (long)gridDim.x * blockDim.x) {
        float v = x[i];
        s += v; q += v * v;
    }
    sS[tid] = s; sQ[tid] = q;
    __syncthreads();
    if (tid < 128) { sS[tid] += sS[tid + 128]; sQ[tid] += sQ[tid + 128]; }
    __syncthreads();
    if (tid < 64) {
        atomicAdd(&stats[d], sS[tid] + sS[tid + 64]);
        atomicAdd(&stats[64 + d], sQ[tid] + sQ[tid + 64]);
    }
}

// ---------- GraphNorm apply. mode: 0 = write, 1 = relu write, 2 = relu accumulate ----------
__global__ void gn_norm_k(const float* __restrict__ x, float* y,
                          const float* __restrict__ stats, const float* __restrict__ w,
                          const float* __restrict__ b, const float* __restrict__ ms,
                          long nrows, int mode) {
    long i = (long)blockIdx.x * blockDim.x + threadIdx.x;
    long tot = nrows * DD;
    if (i >= tot) return;
    int d = (int)(i & 63);
    float n = (float)nrows;
    float mean = stats[d] / n;
    float ex2 = stats[64 + d] / n;
    float m = ms[d];
    float var = ex2 - mean * mean * (2.f * m - m * m);
    float is = rsqrtf(var + 1e-5f);
    float v = (x[i] - m * mean) * is * w[d] + b[d];
    if (mode >= 1) v = fmaxf(v, 0.f);
    if (mode == 2) y[i] += v; else y[i] = v;
}

// ---------- link-pair elementwise product (pos1) ----------
__global__ void pair_mul_k(const float* __restrict__ h, const int* __restrict__ pos,
                           float* __restrict__ y, int nrows) {
    long i = (long)blockIdx.x * blockDim.x + threadIdx.x;
    long tot = (long)nrows * DD;
    if (i >= tot) return;
    int r = (int)(i >> 6), d = (int)(i & 63);
    int p0 = pos[2 * r], p1 = pos[2 * r + 1];
    y[i] = h[(long)p0 * DD + d] * h[(long)p1 * DD + d];
}

// ---------- final: gather pos2 pairs, product, dot with pred_W ----------
__global__ __launch_bounds__(256) void final_k(const float* __restrict__ h, const int* __restrict__ pos2,
                                               const float* __restrict__ pw, const float* __restrict__ pb,
                                               float* __restrict__ out, int nout) {
    long t = (long)blockIdx.x * blockDim.x + threadIdx.x;
    long tot = (long)nout * DD;
    if (t >= tot) return;
    int i = (int)(t >> 6), d = (int)(t & 63);
    int p0 = pos2[2 * i], p1 = pos2[2 * i + 1];
    float v = h[(long)p0 * DD + d] * h[(long)p1 * DD + d] * pw[d];
#pragma unroll
    for (int o = 32; o > 0; o >>= 1) v += __shfl_down(v, o, 64);
    if (d == 0) out[i] = v + pb[0];
}

// ---------- helpers (host) ----------
static void build_csr(const int* rowv, const int* colv, int ne, int n,
                      int* cnt, int* off, int* rows, int* scanb, float* dinv,
                      hipStream_t stream) {
    fill_f32_k<<<256, 256, 0, stream>>>((float*)cnt, 0.f, n);
    hist_k<<<cdiv_l(ne, 256), 256, 0, stream>>>(colv, ne, cnt);
    dinv_from_cnt_k<<<cdiv_l(n, 256), 256, 0, stream>>>(cnt, dinv, n);
    int nb = cdiv_l(n, 1024);
    scan_sums_k<<<nb, 256, 0, stream>>>(cnt, n, scanb);
    scan_tops_k<<<1, 256, 0, stream>>>(scanb, nb);
    scan_apply_k<<<nb, 256, 0, stream>>>(cnt, n, scanb, off);
    csr_fill_k<<<cdiv_l(ne, 256), 256, 0, stream>>>(rowv, colv, ne, off, cnt, rows);
}

extern "C" void kernel_launch(void* const* d_in, const int* in_sizes, int n_in,
                              void* d_out, int out_size, void* d_ws, size_t ws_size,
                              hipStream_t stream) {
    const int* x      = (const int*)d_in[0];
    const int* edge1  = (const int*)d_in[2];
    const int* edge2  = (const int*)d_in[3];
    const int* edge2r = (const int*)d_in[4];
    const int* pos1   = (const int*)d_in[5];
    const int* pos2   = (const int*)d_in[6];
    const float* emb  = (const float*)d_in[7];
    const float* egw  = (const float*)d_in[8];
    const float* egb  = (const float*)d_in[9];
    const float* egm  = (const float*)d_in[10];
    const float* c1W  = (const float*)d_in[11];
    const float* c1b  = (const float*)d_in[12];
    const float* c1gw = (const float*)d_in[13];
    const float* c1gb = (const float*)d_in[14];
    const float* c1gm = (const float*)d_in[15];
    const float* c2W  = (const float*)d_in[16];
    const float* c2b  = (const float*)d_in[17];
    const float* c2gw = (const float*)d_in[18];
    const float* c2gb = (const float*)d_in[19];
    const float* c2gm = (const float*)d_in[20];
    const float* c2rW  = (const float*)d_in[21];
    const float* c2rb  = (const float*)d_in[22];
    const float* c2rgw = (const float*)d_in[23];
    const float* c2rgb = (const float*)d_in[24];
    const float* c2rgm = (const float*)d_in[25];
    const float* predW = (const float*)d_in[26];
    const float* predb = (const float*)d_in[27];
    float* out = (float*)d_out;

    const long SZ = (long)MMn * DD;              // 12.8M floats per node buffer

    float* base  = (float*)d_ws;
    float* B0    = base;
    float* B1    = base + SZ;
    float* B2    = base + 2 * SZ;
    float* dinv1 = base + 3 * SZ;
    float* dinv2 = dinv1 + NN;
    float* dinv2r = dinv2 + MMn;
    float* statsA = dinv2r + MMn;
    float* statsB = statsA + 128;
    int* scanb   = (int*)(statsB + 128);          // 256 ints scan partials
    int* R       = scanb + 256;
    // CSR region (two CSRs live simultaneously at most)
    int* cntA  = R;                 // MMn
    int* offA  = cntA + MMn;        // MMn+1 (+pad)
    int* rowsA = offA + MMn + 8;    // NE2
    int* cntB  = rowsA + NE2;       // MMn
    int* offB  = cntB + MMn;        // MMn+1 (+pad)
    int* rowsB = offB + MMn + 8;    // NE2
    size_t need_csr = (size_t)((char*)(rowsB + NE2) - (char*)base);
    size_t need_old = (3 * SZ + NN + 2 * MMn + 512) * sizeof(float);

    bool use_csr = ws_size >= need_csr;
    if (!use_csr && ws_size < need_old) return;

    if (use_csr) {
        // ---- CSR + dinv for graph 1 ----
        build_csr(edge1, edge1 + NE1, NE1, NN, cntA, offA, rowsA, scanb, dinv1, stream);

        // ---- embedding + GraphNorm (h -> B0) ----
        embed_k<<<cdiv_l((long)NN * DD, 256), 256, 0, stream>>>(x, emb, B0, NN);
        fill_f32_k<<<1, 256, 0, stream>>>(statsA, 0.f, 128);
        gn_stats_k<<<2048, 256, 0, stream>>>(B0, NN, statsA);
        gn_norm_k<<<cdiv_l((long)NN * DD, 256), 256, 0, stream>>>(B0, B0, statsA, egw, egb, egm, NN, 0);

        // ---- conv1 stack on graph 1 (propagate-first, ping-pong B0/B1) ----
        float* h = B0; float* d = B1;
        for (int l = 0; l < 2; ++l) {
            gcn_gather_k<<<cdiv_l(NN, 4), 256, 0, stream>>>(h, offA, rowsA, dinv1, d, NN);
            matmul64_bias_k<<<cdiv_l(NN, 32), 256, 0, stream>>>(d, c1W + (long)l * 4096, c1b + l * 64, d, NN);
            fill_f32_k<<<1, 256, 0, stream>>>(statsA, 0.f, 128);
            gn_stats_k<<<2048, 256, 0, stream>>>(d, NN, statsA);
            gn_norm_k<<<cdiv_l((long)NN * DD, 256), 256, 0, stream>>>(d, d, statsA, c1gw + l * 64, c1gb + l * 64, c1gm + l * 64, NN, 1);
            float* t = h; h = d; d = t;
        }

        // ---- link-pair product -> M rows ----
        float* h2 = d;  // the free buffer among B0/B1
        pair_mul_k<<<cdiv_l((long)MMn * DD, 256), 256, 0, stream>>>(h, pos1, h2, MMn);

        // ---- CSRs + dinv for graph 2 (fwd into A slots, rev into B slots) ----
        build_csr(edge2, edge2 + NE2, NE2, MMn, cntA, offA, rowsA, scanb, dinv2, stream);
        build_csr(edge2r, edge2r + NE2, NE2, MMn, cntB, offB, rowsB, scanb, dinv2r, stream);

        // ---- dual-branch conv2 stack ----
        float* fA = h;   // free N-sized buffer (B0 or B1)
        float* fB = B2;
        for (int l = 0; l < 2; ++l) {
            gcn_gather_k<<<cdiv_l(MMn, 4), 256, 0, stream>>>(h2, offA, rowsA, dinv2, fA, MMn);
            matmul64_bias_k<<<cdiv_l(MMn, 32), 256, 0, stream>>>(fA, c2W + (long)l * 4096, c2b + l * 64, fA, MMn);
            fill_f32_k<<<1, 256, 0, stream>>>(statsA, 0.f, 256);  // zero statsA+statsB
            gn_stats_k<<<2048, 256, 0, stream>>>(fA, MMn, statsA);
            gn_norm_k<<<cdiv_l((long)MMn * DD, 256), 256, 0, stream>>>(fA, fA, statsA, c2gw + l * 64, c2gb + l * 64, c2gm + l * 64, MMn, 1);

            gcn_gather_k<<<cdiv_l(MMn, 4), 256, 0, stream>>>(h2, offB, rowsB, dinv2r, fB, MMn);
            matmul64_bias_k<<<cdiv_l(MMn, 32), 256, 0, stream>>>(fB, c2rW + (long)l * 4096, c2rb + l * 64, fB, MMn);
            gn_stats_k<<<2048, 256, 0, stream>>>(fB, MMn, statsB);
            gn_norm_k<<<cdiv_l((long)MMn * DD, 256), 256, 0, stream>>>(fB, fA, statsB, c2rgw + l * 64, c2rgb + l * 64, c2rgm + l * 64, MMn, 2);

            float* t = h2; h2 = fA; fA = t;   // fB reused
        }

        final_k<<<cdiv_l((long)out_size * DD, 256), 256, 0, stream>>>(h2, pos2, predW, predb, out, out_size);
        return;
    }

    // ================= fallback: round-1 atomic path (propagate-first) =================
    fill_f32_k<<<1024, 256, 0, stream>>>(dinv1, 1.0f, (long)(NN + 2 * MMn));
    count_deg_k<<<cdiv_l(NE1, 256), 256, 0, stream>>>(edge1 + NE1, NE1, dinv1);
    count_deg_k<<<cdiv_l(NE2, 256), 256, 0, stream>>>(edge2 + NE2, NE2, dinv2);
    count_deg_k<<<cdiv_l(NE2, 256), 256, 0, stream>>>(edge2r + NE2, NE2, dinv2r);
    rsqrt_k<<<cdiv_l(NN + 2 * MMn, 256), 256, 0, stream>>>(dinv1, NN + 2 * MMn);

    embed_k<<<cdiv_l((long)NN * DD, 256), 256, 0, stream>>>(x, emb, B0, NN);
    fill_f32_k<<<1, 256, 0, stream>>>(statsA, 0.f, 128);
    gn_stats_k<<<2048, 256, 0, stream>>>(B0, NN, statsA);
    gn_norm_k<<<cdiv_l((long)NN * DD, 256), 256, 0, stream>>>(B0, B0, statsA, egw, egb, egm, NN, 0);

    float* h = B0; float* d = B1;
    for (int l = 0; l < 2; ++l) {
        scatter_self_k<<<cdiv_l((long)NN * DD, 256), 256, 0, stream>>>(h, dinv1, d, NN);
        scatter_edges_k<<<cdiv_l((long)NE1 * DD, 256), 256, 0, stream>>>(edge1, edge1 + NE1, NE1, h, dinv1, d);
        matmul64_bias_k<<<cdiv_l(NN, 32), 256, 0, stream>>>(d, c1W + (long)l * 4096, c1b + l * 64, d, NN);
        fill_f32_k<<<1, 256, 0, stream>>>(statsA, 0.f, 128);
        gn_stats_k<<<2048, 256, 0, stream>>>(d, NN, statsA);
        gn_norm_k<<<cdiv_l((long)NN * DD, 256), 256, 0, stream>>>(d, d, statsA, c1gw + l * 64, c1gb + l * 64, c1gm + l * 64, NN, 1);
        float* t = h; h = d; d = t;
    }

    float* h2 = d;
    pair_mul_k<<<cdiv_l((long)MMn * DD, 256), 256, 0, stream>>>(h, pos1, h2, MMn);

    float* fA = h; float* fB = B2;
    for (int l = 0; l < 2; ++l) {
        scatter_self_k<<<cdiv_l((long)MMn * DD, 256), 256, 0, stream>>>(h2, dinv2, fA, MMn);
        scatter_edges_k<<<cdiv_l((long)NE2 * DD, 256), 256, 0, stream>>>(edge2, edge2 + NE2, NE2, h2, dinv2, fA);
        matmul64_bias_k<<<cdiv_l(MMn, 32), 256, 0, stream>>>(fA, c2W + (long)l * 4096, c2b + l * 64, fA, MMn);
        fill_f32_k<<<1, 256, 0, stream>>>(statsA, 0.f, 256);
        gn_stats_k<<<2048, 256, 0, stream>>>(fA, MMn, statsA);
        gn_norm_k<<<cdiv_l((long)MMn * DD, 256), 256, 0, stream>>>(fA, fA, statsA, c2gw + l * 64, c2gb + l * 64, c2gm + l * 64, MMn, 1);

        scatter_self_k<<<cdiv_l((long)MMn * DD, 256), 256, 0, stream>>>(h2, dinv2r, fB, MMn);
        scatter_edges_k<<<cdiv_l((long)NE2 * DD, 256), 256, 0, stream>>>(edge2r, edge2r + NE2, NE2, h2, dinv2r, fB);
        matmul64_bias_k<<<cdiv_l(MMn, 32), 256, 0, stream>>>(fB, c2rW + (long)l * 4096, c2rb + l * 64, fB, MMn);
        gn_stats_k<<<2048, 256, 0, stream>>>(fB, MMn, statsB);
        gn_norm_k<<<cdiv_l((long)MMn * DD, 256), 256, 0, stream>>>(fB, fA, statsB, c2rgw + l * 64, c2rgb + l * 64, c2rgm + l * 64, MMn, 2);

        float* t = h2; h2 = fA; fA = t;
    }

    final_k<<<cdiv_l((long)out_size * DD, 256), 256, 0, stream>>>(h2, pos2, predW, predb, out, out_size);
}

// Round 3
// 2850.599 us; speedup vs baseline: 2.0692x; 1.1040x over previous
//
#include <hip/hip_runtime.h>
#include <hip/hip_fp16.h>

#define NN 100000      // nodes graph 1
#define MMn 200000     // nodes graph 2 (link nodes)
#define DD 64
#define NE1 3200000
#define NE2 3200000

typedef unsigned int uint32;

static inline int cdiv_l(long a, long b) { return (int)((a + b - 1) / b); }

// ================= small utility kernels =================
__global__ void fill_i32_k(int* p, int v, long n) {
    long i = (long)blockIdx.x * blockDim.x + threadIdx.x;
    long st = (long)gridDim.x * blockDim.x;
    for (; i < n; i += st) p[i] = v;
}
__global__ void fill_f32_k(float* p, float v, long n) {
    long i = (long)blockIdx.x * blockDim.x + threadIdx.x;
    long st = (long)gridDim.x * blockDim.x;
    for (; i < n; i += st) p[i] = v;
}

// ================= CSR build =================
__global__ void hist1_k(const int* __restrict__ col, int ne, int* __restrict__ cnt) {
    int i = blockIdx.x * blockDim.x + threadIdx.x;
    if (i < ne) atomicAdd(&cnt[col[i]], 1);
}
// one pass over edge2: count by col (fwd CSR) and by row (reverse CSR)
__global__ void hist2_k(const int* __restrict__ e2, int ne,
                        int* __restrict__ cntA, int* __restrict__ cntB) {
    int i = blockIdx.x * blockDim.x + threadIdx.x;
    if (i >= ne) return;
    int r = e2[i], c = e2[ne + i];
    atomicAdd(&cntA[c], 1);
    atomicAdd(&cntB[r], 1);
}
__global__ void dinv_from_cnt_k(const int* __restrict__ cnt, float* __restrict__ dinv, int n) {
    int i = blockIdx.x * blockDim.x + threadIdx.x;
    if (i < n) dinv[i] = rsqrtf((float)cnt[i] + 1.0f);
}
// 2-level exclusive scan
__global__ __launch_bounds__(256) void scan_sums_k(const int* __restrict__ cnt, int n, int* __restrict__ bsum) {
    __shared__ int s[256];
    int b = blockIdx.x, t = threadIdx.x;
    int base = b * 1024 + t * 4;
    int T = 0;
#pragma unroll
    for (int j = 0; j < 4; ++j) { int i = base + j; if (i < n) T += cnt[i]; }
    s[t] = T; __syncthreads();
    for (int o = 128; o > 0; o >>= 1) { if (t < o) s[t] += s[t + o]; __syncthreads(); }
    if (t == 0) bsum[b] = s[0];
}
__global__ __launch_bounds__(256) void scan_tops_k(int* bsum, int nb) {
    __shared__ int s[256];
    int t = threadIdx.x;
    int v = (t < nb) ? bsum[t] : 0;
    s[t] = v; __syncthreads();
    for (int o = 1; o < 256; o <<= 1) {
        int x = (t >= o) ? s[t - o] : 0;
        __syncthreads();
        s[t] += x;
        __syncthreads();
    }
    if (t < nb) bsum[t] = s[t] - v;   // exclusive
}
__global__ __launch_bounds__(256) void scan_apply_k(const int* __restrict__ cnt, int n,
                                                    const int* __restrict__ bpre, int* __restrict__ off) {
    __shared__ int sT[256];
    int b = blockIdx.x, t = threadIdx.x;
    int base = b * 1024 + t * 4;
    int v[4]; int T = 0;
#pragma unroll
    for (int j = 0; j < 4; ++j) { int i = base + j; v[j] = (i < n) ? cnt[i] : 0; T += v[j]; }
    sT[t] = T; __syncthreads();
    for (int o = 1; o < 256; o <<= 1) {
        int x = (t >= o) ? sT[t - o] : 0;
        __syncthreads();
        sT[t] += x;
        __syncthreads();
    }
    int ex = sT[t] - T + bpre[b];
#pragma unroll
    for (int j = 0; j < 4; ++j) {
        int i = base + j;
        if (i < n) off[i] = ex;
        ex += v[j];
        if (i == n - 1) off[n] = ex;
    }
}
__global__ void csr_fill1_k(const int* __restrict__ rowv, const int* __restrict__ colv, int ne,
                            const int* __restrict__ off, int* __restrict__ cnt, int* __restrict__ rows) {
    int i = blockIdx.x * blockDim.x + threadIdx.x;
    if (i >= ne) return;
    int c = colv[i];
    int old = atomicSub(&cnt[c], 1);
    rows[off[c] + old - 1] = rowv[i];
}
__global__ void csr_fill2_k(const int* __restrict__ e2, int ne,
                            const int* __restrict__ offA, int* __restrict__ cntA, int* __restrict__ rowsA,
                            const int* __restrict__ offB, int* __restrict__ cntB, int* __restrict__ rowsB) {
    int i = blockIdx.x * blockDim.x + threadIdx.x;
    if (i >= ne) return;
    int r = e2[i], c = e2[ne + i];
    int oa = atomicSub(&cntA[c], 1);
    rowsA[offA[c] + oa - 1] = r;
    int ob = atomicSub(&cntB[r], 1);
    rowsB[offB[r] + ob - 1] = c;
}

// ================= GraphNorm coefficient (inline, per consumer) =================
__device__ __forceinline__ void gn_coef(const float* __restrict__ stats,
                                        const float* __restrict__ w, const float* __restrict__ b,
                                        const float* __restrict__ ms, float nrows, int d,
                                        float& sc, float& sh) {
    float mean = stats[d] / nrows;
    float ex2 = stats[64 + d] / nrows;
    float m = ms[d];
    float var = ex2 - mean * mean * (2.f * m - m * m);
    float is = rsqrtf(var + 1e-5f);
    sc = is * w[d];
    sh = b[d] - m * mean * sc;
}

// ================= embedding gather (fp32 table -> fp16 h) =================
__global__ void embed_k(const int* __restrict__ x, const float* __restrict__ tab,
                        __half* __restrict__ h) {
    long i = (long)blockIdx.x * blockDim.x + threadIdx.x;
    if (i >= (long)NN * DD) return;
    int r = (int)(i >> 6), d = (int)(i & 63);
    h[i] = __float2half(tab[(long)x[r] * DD + d]);
}

// ================= column stats over fp16 matrix (sum, sumsq) =================
__global__ __launch_bounds__(256) void gn_stats_k(const __half2* __restrict__ xx, long nu,
                                                  float* __restrict__ stats) {
    __shared__ float s0[256], s1[256], q0[256], q1[256];
    int tid = threadIdx.x;
    float a0 = 0.f, a1 = 0.f, b0 = 0.f, b1 = 0.f;
    for (long i = (long)blockIdx.x * 256 + tid; i < nu; i += (long)gridDim.x * 256) {
        __half2 u = xx[i];
        float x0 = __low2float(u), x1 = __high2float(u);
        a0 += x0; b0 += x0 * x0;
        a1 += x1; b1 += x1 * x1;
    }
    s0[tid] = a0; s1[tid] = a1; q0[tid] = b0; q1[tid] = b1;
    __syncthreads();
    for (int o = 128; o >= 32; o >>= 1) {
        if (tid < o) { s0[tid] += s0[tid + o]; s1[tid] += s1[tid + o]; q0[tid] += q0[tid + o]; q1[tid] += q1[tid + o]; }
        __syncthreads();
    }
    if (tid < 32) {
        int d0 = 2 * tid;
        atomicAdd(&stats[d0], s0[tid]);
        atomicAdd(&stats[d0 + 1], s1[tid]);
        atomicAdd(&stats[64 + d0], q0[tid]);
        atomicAdd(&stats[64 + d0 + 1], q1[tid]);
    }
}

// ================= fused GCN layer: gather(+opt norm/relu on reads) + matmul + bias =================
// NORM: 0 = raw input, 1 = affine (GN, no relu), 2 = affine + relu
template <int NORM>
__global__ __launch_bounds__(256) void gcn_fused_k(
    const __half* __restrict__ hsrc, const int* __restrict__ off,
    const int* __restrict__ rows, const float* __restrict__ dinv,
    const float* __restrict__ stats, const float* __restrict__ gw,
    const float* __restrict__ gb, const float* __restrict__ gms, float nprev,
    const float* __restrict__ W, const float* __restrict__ bias,
    __half* __restrict__ Z, int n)
{
    __shared__ float sW[4096];
    __shared__ float sP[256];
    int tid = threadIdx.x;
    for (int i = tid; i < 4096; i += 256) sW[i] = W[i];
    int wr = tid >> 6, d = tid & 63;
    int node = blockIdx.x * 4 + wr;
    float sc = 1.f, sh = 0.f;
    if (NORM) gn_coef(stats, gw, gb, gms, nprev, d, sc, sh);
    float P = 0.f;
    if (node < n) {
        int s = off[node], e = off[node + 1];
        float dc = dinv[node];
        float x = __half2float(hsrc[(long)node * DD + d]);
        if (NORM) { x = fmaf(x, sc, sh); if (NORM == 2) x = fmaxf(x, 0.f); }
        float a0 = x * dc, a1 = 0.f, a2 = 0.f, a3 = 0.f;
        int i = s;
        for (; i + 3 < e; i += 4) {
            int r0 = rows[i], r1 = rows[i + 1], r2 = rows[i + 2], r3 = rows[i + 3];
            float x0 = __half2float(hsrc[(long)r0 * DD + d]);
            float x1 = __half2float(hsrc[(long)r1 * DD + d]);
            float x2 = __half2float(hsrc[(long)r2 * DD + d]);
            float x3 = __half2float(hsrc[(long)r3 * DD + d]);
            float w0 = dinv[r0], w1 = dinv[r1], w2 = dinv[r2], w3 = dinv[r3];
            if (NORM) {
                x0 = fmaf(x0, sc, sh); x1 = fmaf(x1, sc, sh);
                x2 = fmaf(x2, sc, sh); x3 = fmaf(x3, sc, sh);
                if (NORM == 2) {
                    x0 = fmaxf(x0, 0.f); x1 = fmaxf(x1, 0.f);
                    x2 = fmaxf(x2, 0.f); x3 = fmaxf(x3, 0.f);
                }
            }
            a0 = fmaf(x0, w0, a0); a1 = fmaf(x1, w1, a1);
            a2 = fmaf(x2, w2, a2); a3 = fmaf(x3, w3, a3);
        }
        for (; i < e; ++i) {
            int r = rows[i];
            float xx = __half2float(hsrc[(long)r * DD + d]);
            if (NORM) { xx = fmaf(xx, sc, sh); if (NORM == 2) xx = fmaxf(xx, 0.f); }
            a0 = fmaf(xx, dinv[r], a0);
        }
        P = ((a0 + a1) + (a2 + a3)) * dc;
    }
    sP[wr * 64 + d] = P;
    __syncthreads();
    // Z[node][d] = bias[d] + sum_k P[node][k] * W[k][d]
    float z = bias[d];
#pragma unroll
    for (int k = 0; k < 64; ++k) z = fmaf(sP[wr * 64 + k], sW[k * 64 + d], z);
    if (node < n) Z[(long)node * DD + d] = __float2half(z);
}

// ================= link-pair product with fused GN+relu on reads =================
__global__ __launch_bounds__(256) void pair_norm_mul_k(
    const __half* __restrict__ Z2, const int* __restrict__ pos,
    const float* __restrict__ stats, const float* __restrict__ gw,
    const float* __restrict__ gb, const float* __restrict__ gms,
    __half* __restrict__ h2)
{
    int tid = threadIdx.x, wr = tid >> 6, d = tid & 63;
    int idx = blockIdx.x * 4 + wr;
    if (idx >= MMn) return;
    float sc, sh;
    gn_coef(stats, gw, gb, gms, (float)NN, d, sc, sh);
    int p0 = pos[2 * idx], p1 = pos[2 * idx + 1];
    float v0 = fmaxf(fmaf(__half2float(Z2[(long)p0 * DD + d]), sc, sh), 0.f);
    float v1 = fmaxf(fmaf(__half2float(Z2[(long)p1 * DD + d]), sc, sh), 0.f);
    h2[(long)idx * DD + d] = __float2half(v0 * v1);
}

// ================= dual-branch GN+relu+add =================
__global__ __launch_bounds__(256) void dualadd_k(
    const __half2* __restrict__ Za, const __half2* __restrict__ Zb,
    const float* __restrict__ stA, const float* __restrict__ wA, const float* __restrict__ bA, const float* __restrict__ msA,
    const float* __restrict__ stB, const float* __restrict__ wB, const float* __restrict__ bB, const float* __restrict__ msB,
    __half2* __restrict__ hout)
{
    const long nu = (long)MMn * 32;
    int tid = threadIdx.x;
    int d0 = (2 * tid) & 63;
    float scA0, shA0, scA1, shA1, scB0, shB0, scB1, shB1;
    gn_coef(stA, wA, bA, msA, (float)MMn, d0, scA0, shA0);
    gn_coef(stA, wA, bA, msA, (float)MMn, d0 + 1, scA1, shA1);
    gn_coef(stB, wB, bB, msB, (float)MMn, d0, scB0, shB0);
    gn_coef(stB, wB, bB, msB, (float)MMn, d0 + 1, scB1, shB1);
    for (long i = (long)blockIdx.x * 256 + tid; i < nu; i += (long)gridDim.x * 256) {
        __half2 ua = Za[i], ub = Zb[i];
        float a0 = __low2float(ua), a1 = __high2float(ua);
        float c0 = __low2float(ub), c1 = __high2float(ub);
        float o0 = fmaxf(fmaf(a0, scA0, shA0), 0.f) + fmaxf(fmaf(c0, scB0, shB0), 0.f);
        float o1 = fmaxf(fmaf(a1, scA1, shA1), 0.f) + fmaxf(fmaf(c1, scB1, shB1), 0.f);
        hout[i] = __halves2half2(__float2half(o0), __float2half(o1));
    }
}

// ================= final: dual GN+relu+add on reads, pair product, dot predW =================
__global__ __launch_bounds__(256) void final_fused_k(
    const __half* __restrict__ Za, const __half* __restrict__ Zb,
    const int* __restrict__ pos2,
    const float* __restrict__ stA, const float* __restrict__ wA, const float* __restrict__ bA, const float* __restrict__ msA,
    const float* __restrict__ stB, const float* __restrict__ wB, const float* __restrict__ bB, const float* __restrict__ msB,
    const float* __restrict__ pw, const float* __restrict__ pb,
    float* __restrict__ out, int nout)
{
    int tid = threadIdx.x, wr = tid >> 6, d = tid & 63;
    int i = blockIdx.x * 4 + wr;
    if (i >= nout) return;
    float scA, shA, scB, shB;
    gn_coef(stA, wA, bA, msA, (float)MMn, d, scA, shA);
    gn_coef(stB, wB, bB, msB, (float)MMn, d, scB, shB);
    int p0 = pos2[2 * i], p1 = pos2[2 * i + 1];
    float v0 = fmaxf(fmaf(__half2float(Za[(long)p0 * DD + d]), scA, shA), 0.f)
             + fmaxf(fmaf(__half2float(Zb[(long)p0 * DD + d]), scB, shB), 0.f);
    float v1 = fmaxf(fmaf(__half2float(Za[(long)p1 * DD + d]), scA, shA), 0.f)
             + fmaxf(fmaf(__half2float(Zb[(long)p1 * DD + d]), scB, shB), 0.f);
    float v = v0 * v1 * pw[d];
#pragma unroll
    for (int o = 32; o > 0; o >>= 1) v += __shfl_down(v, o, 64);
    if (d == 0) out[i] = v + pb[0];
}

extern "C" void kernel_launch(void* const* d_in, const int* in_sizes, int n_in,
                              void* d_out, int out_size, void* d_ws, size_t ws_size,
                              hipStream_t stream) {
    const int* x      = (const int*)d_in[0];
    const int* edge1  = (const int*)d_in[2];
    const int* edge2  = (const int*)d_in[3];
    const int* pos1   = (const int*)d_in[5];
    const int* pos2   = (const int*)d_in[6];
    const float* emb  = (const float*)d_in[7];
    const float* egw  = (const float*)d_in[8];
    const float* egb  = (const float*)d_in[9];
    const float* egm  = (const float*)d_in[10];
    const float* c1W  = (const float*)d_in[11];
    const float* c1b  = (const float*)d_in[12];
    const float* c1gw = (const float*)d_in[13];
    const float* c1gb = (const float*)d_in[14];
    const float* c1gm = (const float*)d_in[15];
    const float* c2W  = (const float*)d_in[16];
    const float* c2b  = (const float*)d_in[17];
    const float* c2gw = (const float*)d_in[18];
    const float* c2gb = (const float*)d_in[19];
    const float* c2gm = (const float*)d_in[20];
    const float* c2rW  = (const float*)d_in[21];
    const float* c2rb  = (const float*)d_in[22];
    const float* c2rgw = (const float*)d_in[23];
    const float* c2rgb = (const float*)d_in[24];
    const float* c2rgm = (const float*)d_in[25];
    const float* predW = (const float*)d_in[26];
    const float* predb = (const float*)d_in[27];
    float* out = (float*)d_out;

    // ---- workspace layout ----
    char* p = (char*)d_ws;
    const long SZH = (long)MMn * DD;  // elements per fp16 node buffer
    __half* BA = (__half*)p; p += SZH * 2;
    __half* BB = (__half*)p; p += SZH * 2;
    __half* BC = (__half*)p; p += SZH * 2;
    int* cnt1 = (int*)p; p += (long)NN * 4;
    int* cntA = (int*)p; p += (long)MMn * 4;
    int* cntB = (int*)p; p += (long)MMn * 4;
    float* dinv1  = (float*)p; p += (long)NN * 4;
    float* dinv2  = (float*)p; p += (long)MMn * 4;
    float* dinv2r = (float*)p; p += (long)MMn * 4;
    int* off1 = (int*)p; p += (long)(NN + 8) * 4;
    int* offA = (int*)p; p += (long)(MMn + 8) * 4;
    int* offB = (int*)p; p += (long)(MMn + 8) * 4;
    int* rows1 = (int*)p; p += (long)NE1 * 4;
    int* rowsA = (int*)p; p += (long)NE2 * 4;
    int* rowsB = (int*)p; p += (long)NE2 * 4;
    int* scanb = (int*)p; p += 256 * 4;
    float* stats = (float*)p; p += 7 * 128 * 4;   // slots 0..6
    if ((size_t)(p - (char*)d_ws) > ws_size) return;

    // ---- zero counters and stats ----
    fill_i32_k<<<1024, 256, 0, stream>>>(cnt1, 0, (long)(NN + 2 * MMn));   // cnt1,cntA,cntB contiguous
    fill_f32_k<<<1, 256, 0, stream>>>(stats, 0.f, 7 * 128);

    // ---- histograms + dinv ----
    hist1_k<<<cdiv_l(NE1, 256), 256, 0, stream>>>(edge1 + NE1, NE1, cnt1);
    hist2_k<<<cdiv_l(NE2, 256), 256, 0, stream>>>(edge2, NE2, cntA, cntB);
    dinv_from_cnt_k<<<cdiv_l(NN + 2 * MMn, 256), 256, 0, stream>>>(cnt1, dinv1, NN + 2 * MMn);

    // ---- scans + fills (must consume cnt after dinv) ----
    int nb1 = cdiv_l(NN, 1024), nb2 = cdiv_l(MMn, 1024);
    scan_sums_k<<<nb1, 256, 0, stream>>>(cnt1, NN, scanb);
    scan_tops_k<<<1, 256, 0, stream>>>(scanb, nb1);
    scan_apply_k<<<nb1, 256, 0, stream>>>(cnt1, NN, scanb, off1);
    csr_fill1_k<<<cdiv_l(NE1, 256), 256, 0, stream>>>(edge1, edge1 + NE1, NE1, off1, cnt1, rows1);
    scan_sums_k<<<nb2, 256, 0, stream>>>(cntA, MMn, scanb);
    scan_tops_k<<<1, 256, 0, stream>>>(scanb, nb2);
    scan_apply_k<<<nb2, 256, 0, stream>>>(cntA, MMn, scanb, offA);
    scan_sums_k<<<nb2, 256, 0, stream>>>(cntB, MMn, scanb);
    scan_tops_k<<<1, 256, 0, stream>>>(scanb, nb2);
    scan_apply_k<<<nb2, 256, 0, stream>>>(cntB, MMn, scanb, offB);
    csr_fill2_k<<<cdiv_l(NE2, 256), 256, 0, stream>>>(edge2, NE2, offA, cntA, rowsA, offB, cntB, rowsB);

    // ---- embedding -> BA (fp16), stats slot0 ----
    embed_k<<<cdiv_l((long)NN * DD, 256), 256, 0, stream>>>(x, emb, BA);
    gn_stats_k<<<1024, 256, 0, stream>>>((const __half2*)BA, (long)NN * 32, stats);

    // ---- conv1 l0: gather(norm emb, no relu) + mm -> BB, stats slot1 ----
    gcn_fused_k<1><<<cdiv_l(NN, 4), 256, 0, stream>>>(BA, off1, rows1, dinv1,
        stats, egw, egb, egm, (float)NN, c1W, c1b, BB, NN);
    gn_stats_k<<<1024, 256, 0, stream>>>((const __half2*)BB, (long)NN * 32, stats + 128);

    // ---- conv1 l1: gather(norm+relu) + mm -> BA, stats slot2 ----
    gcn_fused_k<2><<<cdiv_l(NN, 4), 256, 0, stream>>>(BB, off1, rows1, dinv1,
        stats + 128, c1gw, c1gb, c1gm, (float)NN, c1W + 4096, c1b + 64, BA, NN);
    gn_stats_k<<<1024, 256, 0, stream>>>((const __half2*)BA, (long)NN * 32, stats + 256);

    // ---- pair product (norm+relu fused on reads) -> BC ----
    pair_norm_mul_k<<<cdiv_l(MMn, 4), 256, 0, stream>>>(BA, pos1,
        stats + 256, c1gw + 64, c1gb + 64, c1gm + 64, BC);

    // ---- conv2 l0 ----
    gcn_fused_k<0><<<cdiv_l(MMn, 4), 256, 0, stream>>>(BC, offA, rowsA, dinv2,
        stats, nullptr, nullptr, nullptr, 1.f, c2W, c2b, BB, MMn);
    gn_stats_k<<<1024, 256, 0, stream>>>((const __half2*)BB, (long)MMn * 32, stats + 384);
    gcn_fused_k<0><<<cdiv_l(MMn, 4), 256, 0, stream>>>(BC, offB, rowsB, dinv2r,
        stats, nullptr, nullptr, nullptr, 1.f, c2rW, c2rb, BA, MMn);
    gn_stats_k<<<1024, 256, 0, stream>>>((const __half2*)BA, (long)MMn * 32, stats + 512);
    dualadd_k<<<1024, 256, 0, stream>>>((const __half2*)BB, (const __half2*)BA,
        stats + 384, c2gw, c2gb, c2gm,
        stats + 512, c2rgw, c2rgb, c2rgm, (__half2*)BC);

    // ---- conv2 l1 ----
    gcn_fused_k<0><<<cdiv_l(MMn, 4), 256, 0, stream>>>(BC, offA, rowsA, dinv2,
        stats, nullptr, nullptr, nullptr, 1.f, c2W + 4096, c2b + 64, BB, MMn);
    gn_stats_k<<<1024, 256, 0, stream>>>((const __half2*)BB, (long)MMn * 32, stats + 640);
    gcn_fused_k<0><<<cdiv_l(MMn, 4), 256, 0, stream>>>(BC, offB, rowsB, dinv2r,
        stats, nullptr, nullptr, nullptr, 1.f, c2rW + 4096, c2rb + 64, BA, MMn);
    gn_stats_k<<<1024, 256, 0, stream>>>((const __half2*)BA, (long)MMn * 32, stats + 768);

    // ---- final ----
    final_fused_k<<<cdiv_l(out_size, 4), 256, 0, stream>>>(BB, BA, pos2,
        stats + 640, c2gw + 64, c2gb + 64, c2gm + 64,
        stats + 768, c2rgw + 64, c2rgb + 64, c2rgm + 64,
        predW, predb, out, out_size);
}